// Round 16
// baseline (1958.756 us; speedup 1.0000x reference)
//
#include <hip/hip_runtime.h>
#include <stdint.h>

// Problem constants
#define TT 256      // timesteps per phase
#define BB 256      // batch
#define II 128      // input dim
#define SS 256      // state dim
#define NSTEP (2*TT)
#define NBLK 64     // 16 row-teams x 4 col-blocks (64 cols each)

typedef _Float16 h16;
typedef _Float16 half8 __attribute__((ext_vector_type(8)));
typedef float f32x4 __attribute__((ext_vector_type(4)));

#define SBP 264     // s_buf padded row stride (halves)
#define XBP 136     // xbuf padded row stride (halves)

// Exchange: [parity][team][row 0..15][col_pair 0..127] of u64
//   u64 = { hi: step tag, lo: 2 x fp16 (even col in low half) }
// Tag-in-data (r7/r9/r13/r14/r15-proven). Aligned 8B = single-copy atomic.
// Lap safety: producer writes s_{n+2} into a slot only after gathering ALL
// of s_{n+1}, which requires every team member to have finished reading s_n.
#define XROW 128
#define XTEAM (16 * XROW)        // 2048 u64 per team
#define XPAR  (16 * XTEAM)       // 32768 u64 per parity

__device__ __forceinline__ float sigmoidf_(float z) {
    return __builtin_amdgcn_rcpf(1.0f + __expf(-z));
}
__device__ __forceinline__ float tanhf_(float z) {
    return 1.0f - 2.0f * __builtin_amdgcn_rcpf(1.0f + __expf(2.0f * z));
}

__device__ __forceinline__ void st_ag64(uint64_t* p, uint64_t v) {
    __hip_atomic_store(p, v, __ATOMIC_RELAXED, __HIP_MEMORY_SCOPE_AGENT);
}

// 8 independent 8B device-coherent loads (sc1 = device scope).
#define LD8_OPS                                                             \
        "global_load_dwordx2 %0, %8, off sc1\n\t"                           \
        "global_load_dwordx2 %1, %8, off offset:8 sc1\n\t"                  \
        "global_load_dwordx2 %2, %8, off offset:16 sc1\n\t"                 \
        "global_load_dwordx2 %3, %8, off offset:24 sc1\n\t"                 \
        "global_load_dwordx2 %4, %8, off offset:32 sc1\n\t"                 \
        "global_load_dwordx2 %5, %8, off offset:40 sc1\n\t"                 \
        "global_load_dwordx2 %6, %8, off offset:48 sc1\n\t"                 \
        "global_load_dwordx2 %7, %8, off offset:56 sc1"
#define LD8_OUTS(v)                                                         \
        : "=&v"(v[0]), "=&v"(v[1]), "=&v"(v[2]), "=&v"(v[3]),               \
          "=&v"(v[4]), "=&v"(v[5]), "=&v"(v[6]), "=&v"(v[7])

__device__ __forceinline__ void ld8_issue(const uint64_t* p, uint64_t* v) {
    asm volatile(LD8_OPS LD8_OUTS(v) : "v"(p) : "memory");
}
__device__ __forceinline__ void ld8_wait(const uint64_t* p, uint64_t* v) {
    asm volatile(LD8_OPS "\n\ts_waitcnt vmcnt(0)" LD8_OUTS(v) : "v"(p) : "memory");
}
// wait with gather regs TIED so no consumer is hoisted above it (rule 18)
#define WAIT_TIE8_VM0(v)                                                    \
    asm volatile("s_waitcnt vmcnt(0)"                                       \
        : "+v"(v[0]), "+v"(v[1]), "+v"(v[2]), "+v"(v[3]),                   \
          "+v"(v[4]), "+v"(v[5]), "+v"(v[6]), "+v"(v[7]) :: "memory");      \
    __builtin_amdgcn_sched_barrier(0)

struct Ptrs {
    const float *x;
    const float *Wi, *Ui, *Bi, *Wf, *Uf, *Bf, *Wo, *Uo, *Bo, *Wg, *Ug, *Bg;
    float* out;
    uint32_t* ws;
};

__global__ __launch_bounds__(256, 1) void lstm_persist(Ptrs p) {
    const int tid  = threadIdx.x;
    const int w    = tid >> 6;             // wave 0..3: col-tile within block
    const int lane = tid & 63;
    const int lrow = lane & 15;            // A-row / C-col for this lane
    const int lgrp = lane >> 4;            // 0..3
    const int lk8  = lgrp * 8;             // k sub-offset within 32-chunk
    const int erow = tid >> 4;             // gather ownership (row, pair-oct)
    const int ecol = tid & 15;

    const int team = blockIdx.x >> 2;      // batch rows [team*16, +16)
    const int bc   = blockIdx.x & 3;       // col block: cols [bc*64, +64)
    const int r0   = team * 16;
    const int c0   = bc * 64 + w * 16;     // this wave's 16-col base

    // double-buffered state + x tiles; W fragments staged in LDS (64 KB)
    __shared__ __align__(16) h16 s_buf[2][16 * SBP];   // 16.9 KB
    __shared__ __align__(16) h16 xbuf[2][16 * XBP];    //  8.7 KB
    __shared__ __align__(16) h16 wlds[4][4][4][64 * 8];// 64 KB [w][g][kc][lane*8]

    uint64_t* xch   = (uint64_t*)p.ws;
    uint64_t* slot0 = xch + (size_t)team * XTEAM;
    uint64_t* slot1 = xch + XPAR + (size_t)team * XTEAM;

    const float* Uptr[4] = {p.Ui, p.Uf, p.Uo, p.Ug};
    const float* Wptr[4] = {p.Wi, p.Wf, p.Wo, p.Wg};
    const float* Bptr[4] = {p.Bi, p.Bf, p.Bo, p.Bg};

    // ---- init: zero s_0 buffer ----
    for (int i = tid; i < 16 * SBP; i += 256) s_buf[0][i] = (h16)0.0f;

    // ---- preload ALL 4 gates' U fragments into VGPRs (128 regs) ----
    // B (16x16x32): lane holds B[k=(lane>>4)*8+q][col=lane&15]  (r9-proven)
    half8 bU[4][8];
#pragma unroll
    for (int g = 0; g < 4; ++g) {
        const float* Ug = Uptr[g];
#pragma unroll
        for (int kc = 0; kc < 8; ++kc)
#pragma unroll
            for (int q = 0; q < 8; ++q)
                bU[g][kc][q] = (h16)Ug[(size_t)(kc * 32 + lk8 + q) * SS + c0 + lrow];
    }
    // ---- stage ALL 4 gates' W fragments into LDS (read back each enc step) ----
#pragma unroll
    for (int g = 0; g < 4; ++g) {
        const float* Wg = Wptr[g];
#pragma unroll
        for (int kc = 0; kc < 4; ++kc) {
            half8 f;
#pragma unroll
            for (int q = 0; q < 8; ++q)
                f[q] = (h16)Wg[(size_t)(kc * 32 + lk8 + q) * SS + c0 + lrow];
            *(half8*)&wlds[w][g][kc][lane * 8] = f;
        }
    }
    float bias[4];
#pragma unroll
    for (int g = 0; g < 4; ++g) bias[g] = Bptr[g][c0 + lrow];

    // cell state: lane owns cells (row = lgrp*4+q, col = c0+lrow), q=0..3
    float cst[4] = {0.f, 0.f, 0.f, 0.f};

    // ---- stage x_0 into xbuf[0]; preload x_1 into regs (fp16-packed) ----
    half8 xvh[4];
    {
        const float* xp = p.x + ((size_t)0 * BB + r0 + erow) * II + ecol * 8;
        float4 a = ((const float4*)xp)[0];
        float4 b = ((const float4*)xp)[1];
        half8 h;
        h[0]=(h16)a.x; h[1]=(h16)a.y; h[2]=(h16)a.z; h[3]=(h16)a.w;
        h[4]=(h16)b.x; h[5]=(h16)b.y; h[6]=(h16)b.z; h[7]=(h16)b.w;
        *(half8*)&xbuf[0][erow * XBP + ecol * 8] = h;
        const float* xp1 = p.x + ((size_t)1 * BB + r0 + erow) * II + ecol * 8;
        float4 c = ((const float4*)xp1)[0];
        float4 d = ((const float4*)xp1)[1];
        xvh[0][0]=(h16)c.x; xvh[0][1]=(h16)c.y; xvh[0][2]=(h16)c.z; xvh[0][3]=(h16)c.w;
        xvh[0][4]=(h16)d.x; xvh[0][5]=(h16)d.y; xvh[0][6]=(h16)d.z; xvh[0][7]=(h16)d.w;
        // only one 8-half slot needed per thread per step (ecol*8 window)
    }
    __syncthreads();

    for (int n = 1; n <= NSTEP; ++n) {
        const bool enc = (n <= TT);
        const int  parP = (n - 1) & 1;     // buffers for this step's inputs
        const int  parN = n & 1;           // buffers/slot for this step's outputs

        // ---- [1] MFMA: all 4 gates for this wave's 16 cols ----
        f32x4 acc[4];
#pragma unroll
        for (int g = 0; g < 4; ++g) acc[g] = (f32x4){0.f, 0.f, 0.f, 0.f};
#pragma unroll
        for (int kc = 0; kc < 8; ++kc) {
            half8 a = *(const half8*)&s_buf[parP][lrow * SBP + kc * 32 + lk8];
#pragma unroll
            for (int g = 0; g < 4; ++g)
                acc[g] = __builtin_amdgcn_mfma_f32_16x16x32_f16(a, bU[g][kc], acc[g], 0, 0, 0);
        }
        if (enc) {
#pragma unroll
            for (int kc = 0; kc < 4; ++kc) {
                half8 a = *(const half8*)&xbuf[parP][lrow * XBP + kc * 32 + lk8];
#pragma unroll
                for (int g = 0; g < 4; ++g) {
                    half8 bw = *(const half8*)&wlds[w][g][kc][lane * 8];
                    acc[g] = __builtin_amdgcn_mfma_f32_16x16x32_f16(a, bw, acc[g], 0, 0, 0);
                }
            }
        }

        // ---- [2] gates + state update, in-register on C/D fragments ----
        // C/D: col = c0+lrow, row = lgrp*4+q  (m89-verified)
        float sv[4], ov[4];
#pragma unroll
        for (int q = 0; q < 4; ++q) {
            float zi = acc[0][q] + bias[0];
            float zf = acc[1][q] + bias[1];
            float zo = acc[2][q] + bias[2];
            float zg = acc[3][q] + bias[3];
            float ig = sigmoidf_(zi), fg = sigmoidf_(zf);
            float og = sigmoidf_(zo), gg = tanhf_(zg);
            cst[q] = cst[q] * fg + gg * ig;
            sv[q] = tanhf_(cst[q]) * og;
            ov[q] = og;
        }

        if (n < NSTEP) {
            uint64_t* slotP = parN ? slot1 : slot0;

            // ---- [3] publish s_n FIRST: 4 tagged u64 per even lane ----
            {
                const uint64_t tag = (uint64_t)(uint32_t)n << 32;
#pragma unroll
                for (int q = 0; q < 4; ++q) {
                    float so = __shfl_xor(sv[q], 1);
                    if ((lane & 1) == 0) {
                        uint16_t lo = __builtin_bit_cast(uint16_t, (h16)sv[q]);
                        uint16_t hi = __builtin_bit_cast(uint16_t, (h16)so);
                        uint64_t pk = tag | (uint64_t)((uint32_t)lo | ((uint32_t)hi << 16));
                        st_ag64(slotP + (size_t)(lgrp * 4 + q) * XROW
                                      + bc * 32 + w * 8 + (lrow >> 1), pk);
                    }
                }
            }

            // ---- [4] issue gather of s_n (full row incl. own cols) ----
            const uint64_t* gp = slotP + (size_t)erow * XROW + ecol * 8;
            uint64_t gv[8];
            ld8_issue(gp, gv);

            // ---- [5] off-path: stage x (enc) / out store (dec) ----
            if (enc) {
                if (n < TT) {
                    *(half8*)&xbuf[parN][erow * XBP + ecol * 8] = xvh[0];
                    if (n + 1 < TT) {
                        const float* xp = p.x + ((size_t)(n + 1) * BB + r0 + erow) * II + ecol * 8;
                        float4 a = ((const float4*)xp)[0];
                        float4 b = ((const float4*)xp)[1];
                        xvh[0][0]=(h16)a.x; xvh[0][1]=(h16)a.y; xvh[0][2]=(h16)a.z; xvh[0][3]=(h16)a.w;
                        xvh[0][4]=(h16)b.x; xvh[0][5]=(h16)b.y; xvh[0][6]=(h16)b.z; xvh[0][7]=(h16)b.w;
                    }
                }
            } else {
                const int d = n - TT - 1;
#pragma unroll
                for (int q = 0; q < 4; ++q)
                    p.out[((size_t)d * BB + r0 + lgrp * 4 + q) * SS + c0 + lrow] = ov[q];
            }

            // ---- [6] wait + retry; fill s_buf[parN] ----
            {
                WAIT_TIE8_VM0(gv);
                const uint32_t want = (uint32_t)n;
                for (;;) {
                    bool fresh = true;
#pragma unroll
                    for (int j = 0; j < 8; ++j)
                        fresh = fresh && ((uint32_t)(gv[j] >> 32) == want);
                    if (__builtin_expect(fresh, 1)) break;
                    ld8_wait(gp, gv);
                }
                uint4 q0 = make_uint4((uint32_t)gv[0], (uint32_t)gv[1],
                                      (uint32_t)gv[2], (uint32_t)gv[3]);
                uint4 q1 = make_uint4((uint32_t)gv[4], (uint32_t)gv[5],
                                      (uint32_t)gv[6], (uint32_t)gv[7]);
                *(uint4*)&s_buf[parN][erow * SBP + ecol * 16]     = q0;
                *(uint4*)&s_buf[parN][erow * SBP + ecol * 16 + 8] = q1;
            }
            __syncthreads();   // single barrier: s_buf/xbuf[parN] ready
        } else {
            // final step: output only
            const int d = n - TT - 1;
#pragma unroll
            for (int q = 0; q < 4; ++q)
                p.out[((size_t)d * BB + r0 + lgrp * 4 + q) * SS + c0 + lrow] = ov[q];
        }
    }
}

extern "C" void kernel_launch(void* const* d_in, const int* in_sizes, int n_in,
                              void* d_out, int out_size, void* d_ws, size_t ws_size,
                              hipStream_t stream) {
    Ptrs p;
    p.x  = (const float*)d_in[0];
    p.Wi = (const float*)d_in[1];  p.Ui = (const float*)d_in[2];  p.Bi = (const float*)d_in[3];
    p.Wf = (const float*)d_in[4];  p.Uf = (const float*)d_in[5];  p.Bf = (const float*)d_in[6];
    p.Wo = (const float*)d_in[7];  p.Uo = (const float*)d_in[8];  p.Bo = (const float*)d_in[9];
    p.Wg = (const float*)d_in[10]; p.Ug = (const float*)d_in[11]; p.Bg = (const float*)d_in[12];
    p.out = (float*)d_out;
    p.ws  = (uint32_t*)d_ws;

    // zero tags each launch -> no stale-tag acceptance across replays
    hipMemsetAsync(d_ws, 0, (size_t)2 * XPAR * sizeof(uint64_t), stream);

    // coop preferred; plain-launch fallback (64 blocks on 256 CUs are
    // co-resident either way; protocol needs no grid primitives)
    void* args[] = {&p};
    hipError_t e = hipLaunchCooperativeKernel(lstm_persist, dim3(NBLK), dim3(256),
                                              args, 0, stream);
    if (e != hipSuccess) {
        hipLaunchKernelGGL(lstm_persist, dim3(NBLK), dim3(256), 0, stream, p);
    }
}

// Round 17
// 1307.999 us; speedup vs baseline: 1.4975x; 1.4975x over previous
//
#include <hip/hip_runtime.h>
#include <stdint.h>

// Problem constants
#define TT 256      // timesteps per phase
#define BB 256      // batch
#define II 128      // input dim
#define SS 256      // state dim
#define NSTEP (2*TT)
#define NBLK 256    // 16 teams x 16 col-blocks (r9-proven shape)

typedef _Float16 h16;
typedef _Float16 half8 __attribute__((ext_vector_type(8)));
typedef float f32x4 __attribute__((ext_vector_type(4)));

#define SBP 264     // s_buf padded row stride (halves)
#define XBP 136     // xbuf padded row stride (halves)

// Exchange: [parity][team][row 0..15][col_pair 0..127] of u64
//   u64 = { hi: step tag, lo: 2 x fp16 (even col in low half) }
// Tag-in-data (r7/r9/r13/r14/r15/r16-proven): no flags, no drains, no extra
// barriers. Aligned 8B accesses are single-copy atomic. Lap safety: a
// producer writes s_{n+2} into a slot only after gathering ALL of s_{n+1},
// which requires every team member to have finished reading s_n.
#define XROW 128
#define XTEAM (16 * XROW)        // 2048 u64 per team
#define XPAR  (16 * XTEAM)       // 32768 u64 per parity

__device__ __forceinline__ float sigmoidf_(float z) {
    return __builtin_amdgcn_rcpf(1.0f + __expf(-z));
}
__device__ __forceinline__ float tanhf_(float z) {
    return 1.0f - 2.0f * __builtin_amdgcn_rcpf(1.0f + __expf(2.0f * z));
}

__device__ __forceinline__ void st_ag64(uint64_t* p, uint64_t v) {
    __hip_atomic_store(p, v, __ATOMIC_RELAXED, __HIP_MEMORY_SCOPE_AGENT);
}

// Batched 8x8B device-coherent load, ONE wait (r9-proven; no issue/wait
// split, no sched_barrier pin -- r15 showed those regress here).
__device__ __forceinline__ void ld8u64_sc1(const uint64_t* p, uint64_t* v) {
    asm volatile(
        "global_load_dwordx2 %0, %8, off sc1\n\t"
        "global_load_dwordx2 %1, %8, off offset:8 sc1\n\t"
        "global_load_dwordx2 %2, %8, off offset:16 sc1\n\t"
        "global_load_dwordx2 %3, %8, off offset:24 sc1\n\t"
        "global_load_dwordx2 %4, %8, off offset:32 sc1\n\t"
        "global_load_dwordx2 %5, %8, off offset:40 sc1\n\t"
        "global_load_dwordx2 %6, %8, off offset:48 sc1\n\t"
        "global_load_dwordx2 %7, %8, off offset:56 sc1\n\t"
        "s_waitcnt vmcnt(0)"
        : "=&v"(v[0]), "=&v"(v[1]), "=&v"(v[2]), "=&v"(v[3]),
          "=&v"(v[4]), "=&v"(v[5]), "=&v"(v[6]), "=&v"(v[7])
        : "v"(p) : "memory");
}

struct Ptrs {
    const float *x;
    const float *Wi, *Ui, *Bi, *Wf, *Uf, *Bf, *Wo, *Uo, *Bo, *Wg, *Ug, *Bg;
    float* out;
    uint32_t* ws;
};

__global__ __launch_bounds__(256, 1) void lstm_persist(Ptrs p) {
    const int bid  = blockIdx.x;
    const int tid  = threadIdx.x;
    const int wave = tid >> 6;            // gate: 0=i 1=f 2=o 3=g
    const int lane = tid & 63;
    const int lrow = lane & 15;           // A-row / B-col within tile
    const int lk8  = (lane >> 4) * 8;     // k sub-offset within 32-chunk
    const int erow = tid >> 4;            // elementwise (row,col) ownership
    const int ecol = tid & 15;

    const int team = bid >> 4;            // batch rows [team*16, +16)
    const int c    = bid & 15;            // col block  [c*16, +16)
    const int r0   = team * 16;
    const int c0   = c * 16;

    __shared__ __align__(16) h16 s_buf[16 * SBP];
    __shared__ __align__(16) h16 xbuf[16 * XBP];
    __shared__ float zbuf[4][16][17];
    __shared__ float biasLds[4][16];

    uint64_t* xch   = (uint64_t*)p.ws;
    uint64_t* slot0 = xch + (size_t)team * XTEAM;
    uint64_t* slot1 = xch + XPAR + (size_t)team * XTEAM;

    const float* Uptr[4] = {p.Ui, p.Uf, p.Uo, p.Ug};
    const float* Wptr[4] = {p.Wi, p.Wf, p.Wo, p.Wg};
    const float* Bptr[4] = {p.Bi, p.Bf, p.Bo, p.Bg};

    if (tid < 64) biasLds[tid >> 4][tid & 15] = Bptr[tid >> 4][c0 + (tid & 15)];
    for (int idx = tid; idx < 16 * SBP; idx += 256) s_buf[idx] = (h16)0.0f;

    // B (16x16x32): lane holds B[k=(lane>>4)*8+q][col=lane&15] (r9-proven)
    const float* Ug = Uptr[wave];
    const float* Wg = Wptr[wave];
    half8 bU[8];
#pragma unroll
    for (int kc = 0; kc < 8; ++kc)
#pragma unroll
        for (int q = 0; q < 8; ++q)
            bU[kc][q] = (h16)Ug[(size_t)(kc * 32 + lk8 + q) * SS + c0 + lrow];
    half8 bW[4];
#pragma unroll
    for (int kc = 0; kc < 4; ++kc)
#pragma unroll
        for (int q = 0; q < 8; ++q)
            bW[kc][q] = (h16)Wg[(size_t)(kc * 32 + lk8 + q) * SS + c0 + lrow];

    float cst = 0.0f;   // cell state owned by this thread: (erow, ecol)

    // ---- stage x tile for t=0; prefetch t=1 ----
    float4 pa, pb;
    {
        const float* xp = p.x + ((size_t)0 * BB + r0 + erow) * II + ecol * 8;
        pa = ((const float4*)xp)[0];
        pb = ((const float4*)xp)[1];
        half8 h;
        h[0]=(h16)pa.x; h[1]=(h16)pa.y; h[2]=(h16)pa.z; h[3]=(h16)pa.w;
        h[4]=(h16)pb.x; h[5]=(h16)pb.y; h[6]=(h16)pb.z; h[7]=(h16)pb.w;
        *(half8*)&xbuf[erow * XBP + ecol * 8] = h;
        const float* xp1 = p.x + ((size_t)1 * BB + r0 + erow) * II + ecol * 8;
        pa = ((const float4*)xp1)[0];
        pb = ((const float4*)xp1)[1];
    }
    __syncthreads();

    for (int n = 1; n <= NSTEP; ++n) {
        const bool enc = (n <= TT);

        // ---- MFMA: z[16x16] for gate `wave` ----
        f32x4 acc = {0.f, 0.f, 0.f, 0.f};
#pragma unroll
        for (int kc = 0; kc < 8; ++kc) {
            half8 a = *(const half8*)&s_buf[lrow * SBP + kc * 32 + lk8];
            acc = __builtin_amdgcn_mfma_f32_16x16x32_f16(a, bU[kc], acc, 0, 0, 0);
        }
        if (enc) {
#pragma unroll
            for (int kc = 0; kc < 4; ++kc) {
                half8 a = *(const half8*)&xbuf[lrow * XBP + kc * 32 + lk8];
                acc = __builtin_amdgcn_mfma_f32_16x16x32_f16(a, bW[kc], acc, 0, 0, 0);
            }
        }
        // C/D layout: col=lane&15, row=(lane>>4)*4+reg (m89-verified)
#pragma unroll
        for (int q = 0; q < 4; ++q)
            zbuf[wave][(lane >> 4) * 4 + q][lrow] = acc[q];
        __syncthreads();   // barrier A: zbuf ready; s_buf/xbuf reads done

        // ---- gates / state update ----
        float zi = zbuf[0][erow][ecol] + biasLds[0][ecol];
        float zf = zbuf[1][erow][ecol] + biasLds[1][ecol];
        float zo = zbuf[2][erow][ecol] + biasLds[2][ecol];
        float zg = zbuf[3][erow][ecol] + biasLds[3][ecol];
        float ig = sigmoidf_(zi), fg = sigmoidf_(zf);
        float og = sigmoidf_(zo), gg = tanhf_(zg);
        cst = cst * fg + gg * ig;
        float sv = tanhf_(cst) * og;

        h16 svh = (h16)sv;
        s_buf[erow * SBP + c * 16 + ecol] = svh;   // own slice direct to LDS

        if (n < NSTEP) {
            uint64_t* slotP = (n & 1) ? slot1 : slot0;

            // ---- publish s_n FIRST (team critical path) ----
            {
                float so = __shfl_xor(sv, 1);
                if ((tid & 1) == 0) {
                    uint16_t lo = __builtin_bit_cast(uint16_t, svh);
                    uint16_t hi = __builtin_bit_cast(uint16_t, (h16)so);
                    uint64_t pk = ((uint64_t)(uint32_t)n << 32)
                                | (uint64_t)((uint32_t)lo | ((uint32_t)hi << 16));
                    st_ag64(slotP + (size_t)erow * XROW + c * 8 + (ecol >> 1), pk);
                }
            }

            // ---- off-path work BEFORE the gather (r14-enc proven: the
            //      publish-commit + first-RT latency hides under it) ----
            if (enc) {
                if (n < TT) {
                    half8 h;
                    h[0]=(h16)pa.x; h[1]=(h16)pa.y; h[2]=(h16)pa.z; h[3]=(h16)pa.w;
                    h[4]=(h16)pb.x; h[5]=(h16)pb.y; h[6]=(h16)pb.z; h[7]=(h16)pb.w;
                    *(half8*)&xbuf[erow * XBP + ecol * 8] = h;   // xbuf reads done at barrier A
                    if (n + 1 < TT) {
                        const float* xp = p.x + ((size_t)(n + 1) * BB + r0 + erow) * II + ecol * 8;
                        pa = ((const float4*)xp)[0];
                        pb = ((const float4*)xp)[1];
                    }
                }
            } else {
                const int d = n - TT - 1;
                p.out[((size_t)d * BB + r0 + erow) * SS + c0 + ecol] = og;
            }

            // ---- gather s_n (batched passes, one wait each; r9-proven) ----
            if (ecol != c) {
                const uint64_t* gp = slotP + (size_t)erow * XROW + ecol * 8;
                const uint32_t want = (uint32_t)n;
                uint64_t gv[8];
                ld8u64_sc1(gp, gv);
                for (;;) {
                    bool fresh = true;
#pragma unroll
                    for (int j = 0; j < 8; ++j)
                        fresh = fresh && ((uint32_t)(gv[j] >> 32) == want);
                    if (__builtin_expect(fresh, 1)) break;
                    ld8u64_sc1(gp, gv);
                }
                uint4 q0 = make_uint4((uint32_t)gv[0], (uint32_t)gv[1],
                                      (uint32_t)gv[2], (uint32_t)gv[3]);
                uint4 q1 = make_uint4((uint32_t)gv[4], (uint32_t)gv[5],
                                      (uint32_t)gv[6], (uint32_t)gv[7]);
                *(uint4*)&s_buf[erow * SBP + ecol * 16]     = q0;
                *(uint4*)&s_buf[erow * SBP + ecol * 16 + 8] = q1;
            }
            __syncthreads();   // barrier B: s_buf/xbuf complete for step n+1
        } else {
            // final step: output only
            const int d = n - TT - 1;
            p.out[((size_t)d * BB + r0 + erow) * SS + c0 + ecol] = og;
        }
    }
}

extern "C" void kernel_launch(void* const* d_in, const int* in_sizes, int n_in,
                              void* d_out, int out_size, void* d_ws, size_t ws_size,
                              hipStream_t stream) {
    Ptrs p;
    p.x  = (const float*)d_in[0];
    p.Wi = (const float*)d_in[1];  p.Ui = (const float*)d_in[2];  p.Bi = (const float*)d_in[3];
    p.Wf = (const float*)d_in[4];  p.Uf = (const float*)d_in[5];  p.Bf = (const float*)d_in[6];
    p.Wo = (const float*)d_in[7];  p.Uo = (const float*)d_in[8];  p.Bo = (const float*)d_in[9];
    p.Wg = (const float*)d_in[10]; p.Ug = (const float*)d_in[11]; p.Bg = (const float*)d_in[12];
    p.out = (float*)d_out;
    p.ws  = (uint32_t*)d_ws;

    // zero tags each launch -> no stale-tag acceptance, replay-safe
    hipMemsetAsync(d_ws, 0, (size_t)2 * XPAR * sizeof(uint64_t), stream);

    // r9-proven coop shape; plain-launch fallback (protocol needs only
    // de-facto co-residency of 256 blocks on 256 CUs).
    void* args[] = {&p};
    hipError_t e = hipLaunchCooperativeKernel(lstm_persist, dim3(NBLK), dim3(256),
                                              args, 0, stream);
    if (e != hipSuccess) {
        hipLaunchKernelGGL(lstm_persist, dim3(NBLK), dim3(256), 0, stream, p);
    }
}